// Round 11
// baseline (37.069 us; speedup 1.0000x reference)
//
#include <hip/hip_runtime.h>

typedef float f32x4 __attribute__((ext_vector_type(4)));
typedef int   i32x4 __attribute__((ext_vector_type(4)));

#define KC 512
#define DC 64
#define HWs 4096
#define NPTS 131072
#define PPW 16                 // points per wave
#define NBLK 1024              // 8 waves/block * 16 pts = 128 pts/block
#define SE 512.0f              // codebook scale (e' = 512 e)
#define SZ 64.0f               // z scale (z' = 64 z, |z'|<448 at 7 sigma)
#define CBASE 4096.0f          // keeps packed scores positive

template <bool HI>
static __device__ inline int pk8(float a, float b, int old) {
    return __builtin_amdgcn_cvt_pk_fp8_f32(a, b, old, HI);
}
static __device__ inline long mk64(int lo, int hi) {
    return (long)(((unsigned long)(unsigned)hi << 32) | (unsigned)lo);
}
static __device__ inline int pack4(float a, float b, float c, float d) {
    int w = pk8<false>(a, b, 0);
    return pk8<true>(c, d, w);
}

// --- main: in-block staging (tile-order, conflict-free), MFMA search -------
// score = CBASE - 0.5*SZ*SE*||e||^2 + z'.e'  (argmax == argmin distance)
// norm folded into ini-MFMA: A byte0 (g==0 lanes) = fp8(-||e'||^2/16),
// B byte0 = fp8(1.0), C = CBASE broadcast.
__global__ __launch_bounds__(512, 8) void vq_search(const float* __restrict__ z,
                                                    const float* __restrict__ cbf,
                                                    float* __restrict__ outq,
                                                    float* __restrict__ partial) {
    __shared__ unsigned int cbL[KC * 16];   // 32 KB fp8 image, tile order:
                                            // byte j*16, j = t*64 + g*16 + pl
    __shared__ unsigned int iniT[128];      // 512 ini bytes, [pl][t]
    __shared__ float redL[8];
    const int tid = threadIdx.x;
    const int lane = tid & 63, wid = tid >> 6;
    const int g = lane >> 4, pl = lane & 15;

    // ---- stage: fp32 codebook -> fp8 LDS in tile order + ini bytes --------
    for (int pass = 0; pass < 4; ++pass) {
        const int i = pass * 512 + tid;          // 0..2047 = t*64 + g*16 + pl
        const int r = ((i >> 6) << 4) | (i & 15);     // code row 16t+pl
        const int c = (i >> 4) & 3;                   // chunk = g
        const float* src = cbf + (size_t)r * DC + 8 * c;
        f32x4 a0 = *(const f32x4*)(src);
        f32x4 a1 = *(const f32x4*)(src + 4);
        f32x4 b0 = *(const f32x4*)(src + 32);
        f32x4 b1 = *(const f32x4*)(src + 36);
        a0 *= SE; a1 *= SE; b0 *= SE; b1 *= SE;
        i32x4 w = {pack4(a0[0], a0[1], a0[2], a0[3]),
                   pack4(a1[0], a1[1], a1[2], a1[3]),
                   pack4(b0[0], b0[1], b0[2], b0[3]),
                   pack4(b1[0], b1[1], b1[2], b1[3])};
        *(i32x4*)((char*)cbL + (size_t)i * 16) = w;   // linear in lane: no conflicts
        float ss = 0.f;
#pragma unroll
        for (int k = 0; k < 4; ++k) {
            ss = fmaf(a0[k], a0[k], ss); ss = fmaf(a1[k], a1[k], ss);
            ss = fmaf(b0[k], b0[k], ss); ss = fmaf(b1[k], b1[k], ss);
        }
        ss += __shfl_xor(ss, 16, 64);                 // sum over the 4 chunks
        ss += __shfl_xor(ss, 32, 64);                 // (lanes pl+16c, same pl)
        if (c == 0) {
            int w8 = pk8<false>(-0.0625f * ss, 0.f, 0);
            ((unsigned char*)iniT)[(r & 15) * 32 + (r >> 4)] = (unsigned char)(w8 & 0xff);
        }
    }
    __syncthreads();

    const int wg = blockIdx.x * 8 + wid;         // 0..8191
    const int p0 = wg * PPW;
    const int b  = p0 >> 12;                     // 16 | 4096 -> same b per wave
    const int s0 = (p0 & (HWs - 1)) + pl;
    const float* zbase = z + (size_t)b * (DC * HWs) + s0;

    // ---- z load + immediate fp8 pack (zt dies here; epilogue reloads z) ---
    long zfr0, zfr1;
    {
        float zt[16];
#pragma unroll
        for (int j = 0; j < 8; ++j) {
            zt[j]     = zbase[(size_t)(8 * g + j) * HWs];
            zt[8 + j] = zbase[(size_t)(32 + 8 * g + j) * HWs];
        }
        zfr0 = mk64(pack4(SZ * zt[0],  SZ * zt[1],  SZ * zt[2],  SZ * zt[3]),
                    pack4(SZ * zt[4],  SZ * zt[5],  SZ * zt[6],  SZ * zt[7]));
        zfr1 = mk64(pack4(SZ * zt[8],  SZ * zt[9],  SZ * zt[10], SZ * zt[11]),
                    pack4(SZ * zt[12], SZ * zt[13], SZ * zt[14], SZ * zt[15]));
    }

    // per-lane ini bytes for codes 16t+pl, t=0..31 (transposed rows)
    const i32x4 iw0 = *(const i32x4*)((const char*)iniT + pl * 32);
    const i32x4 iw1 = *(const i32x4*)((const char*)iniT + pl * 32 + 16);
    const unsigned gmask = (g == 0) ? 0xffu : 0u;
    const long bunit = (g == 0) ? 0x38L : 0L;    // fp8 1.0 at k=0
    const f32x4 cb4 = {CBASE, CBASE, CBASE, CBASE};
    const char* cbbase = (const char*)cbL + lane * 16;

    unsigned best = 0u;
#pragma unroll
    for (int t = 0; t < 32; ++t) {
        const unsigned wrd = (t < 16) ? (unsigned)iw0[(t >> 2) & 3]
                                      : (unsigned)iw1[((t - 16) >> 2) & 3];
        const long a_ini = (long)((wrd >> ((t & 3) * 8)) & gmask);
        i32x4 aw = *(const i32x4*)(cbbase + (size_t)t * 1024);   // linear: conflict-free
        long A0 = mk64(aw[0], aw[1]);            // dims 8g..8g+7
        long A1 = mk64(aw[2], aw[3]);            // dims 32+8g..32+8g+7
        f32x4 acc = __builtin_amdgcn_mfma_f32_16x16x32_fp8_fp8(a_ini, bunit, cb4, 0, 0, 0);
        acc = __builtin_amdgcn_mfma_f32_16x16x32_fp8_fp8(A0, zfr0, acc, 0, 0, 0);
        acc = __builtin_amdgcn_mfma_f32_16x16x32_fp8_fp8(A1, zfr1, acc, 0, 0, 0);
#pragma unroll
        for (int j = 0; j < 4; ++j) {
            const unsigned code = (unsigned)(16 * t + 4 * g + j);
            unsigned u = __builtin_bit_cast(unsigned, acc[j]) | code;
            best = best > u ? best : u;
        }
    }

    // argmax across the 4 g-groups holding the same point
#pragma unroll
    for (int m = 16; m <= 32; m <<= 1) {
        unsigned o = (unsigned)__shfl_xor((int)best, m, 64);
        best = best > o ? best : o;
    }
    const int bidx = best & 511;

    // ---- epilogue: exact fp32 code row, write out, loss (z reloaded) ------
    const float* qp = cbf + (size_t)bidx * DC + 8 * g;
    f32x4 q0 = *(const f32x4*)(qp);
    f32x4 q1 = *(const f32x4*)(qp + 4);
    f32x4 q2 = *(const f32x4*)(qp + 32);
    f32x4 q3 = *(const f32x4*)(qp + 36);
    float* obase = outq + (size_t)b * (DC * HWs) + s0;
    float err = 0.f;
#pragma unroll
    for (int j = 0; j < 4; ++j) {
        size_t o0 = (size_t)(8 * g + j) * HWs;
        size_t o1 = (size_t)(8 * g + 4 + j) * HWs;
        size_t o2 = (size_t)(32 + 8 * g + j) * HWs;
        size_t o3 = (size_t)(32 + 8 * g + 4 + j) * HWs;
        float d0 = q0[j] - zbase[o0]; obase[o0] = q0[j]; err = fmaf(d0, d0, err);
        float d1 = q1[j] - zbase[o1]; obase[o1] = q1[j]; err = fmaf(d1, d1, err);
        float d2 = q2[j] - zbase[o2]; obase[o2] = q2[j]; err = fmaf(d2, d2, err);
        float d3 = q3[j] - zbase[o3]; obase[o3] = q3[j]; err = fmaf(d3, d3, err);
    }

    // wave reduce -> block reduce -> one partial per block
#pragma unroll
    for (int off = 32; off; off >>= 1) err += __shfl_down(err, off, 64);
    if (lane == 0) redL[wid] = err;
    __syncthreads();
    if (tid == 0) {
        float s = 0.f;
#pragma unroll
        for (int k = 0; k < 8; ++k) s += redL[k];
        partial[blockIdx.x] = s;
    }
}

// --- final loss reduction ---------------------------------------------------
__global__ __launch_bounds__(256) void vq_loss(const float* __restrict__ partial,
                                               float* __restrict__ loss_out) {
    float s = 0.f;
#pragma unroll
    for (int q = 0; q < NBLK / 256; ++q) s += partial[q * 256 + threadIdx.x];
#pragma unroll
    for (int off = 32; off; off >>= 1) s += __shfl_down(s, off, 64);
    __shared__ float red[4];
    if ((threadIdx.x & 63) == 0) red[threadIdx.x >> 6] = s;
    __syncthreads();
    if (threadIdx.x == 0)
        loss_out[0] = 1.25f * ((red[0] + red[1]) + (red[2] + red[3])) / 8388608.0f;
}

extern "C" void kernel_launch(void* const* d_in, const int* in_sizes, int n_in,
                              void* d_out, int out_size, void* d_ws, size_t ws_size,
                              hipStream_t stream) {
    const float* z   = (const float*)d_in[0];    // [32,64,64,64] f32
    const float* cbf = (const float*)d_in[1];    // [512,64] f32
    float* outq = (float*)d_out;                 // 8388608 + 1 (loss)
    float* loss = outq + 8388608;
    float* partial = (float*)d_ws;               // 1024 f32

    vq_search<<<NBLK, 512, 0, stream>>>(z, cbf, outq, partial);
    vq_loss<<<1, 256, 0, stream>>>(partial, loss);
}

// Round 12
// 33.826 us; speedup vs baseline: 1.0959x; 1.0959x over previous
//
#include <hip/hip_runtime.h>

typedef float f32x4 __attribute__((ext_vector_type(4)));
typedef int   i32x4 __attribute__((ext_vector_type(4)));

#define KC 512
#define DC 64
#define HWs 4096
#define NPTS 131072
#define NBLK 512               // 8 waves/block, 32 pts/wave = 256 pts/block
#define SE 512.0f              // codebook scale (e' = 512 e)
#define SZ 64.0f               // z scale (z' = 64 z)
#define CBASE 4096.0f          // keeps packed scores positive

template <bool HI>
static __device__ inline int pk8(float a, float b, int old) {
    return __builtin_amdgcn_cvt_pk_fp8_f32(a, b, old, HI);
}
static __device__ inline long mk64(int lo, int hi) {
    return (long)(((unsigned long)(unsigned)hi << 32) | (unsigned)lo);
}
static __device__ inline int pack4(float a, float b, float c, float d) {
    int w = pk8<false>(a, b, 0);
    return pk8<true>(c, d, w);
}

// --- fused: staging + MFMA search + atomic loss ----------------------------
// score = CBASE - 0.5*SZ*SE*||e||^2 + z'.e'  (argmax == argmin distance)
// norm folded into ini-MFMA (A byte0 on g==0 = fp8(-||e'||^2/16), B byte0 = 1.0).
// LDS image in tile order: byte j*16, j = t*64 + g*16 + pl  ->  the loop's
// ds_read_b128 at lane*16 + t*1024 is linear in lane (conflict-free).
__global__ __launch_bounds__(512, 4) void vq_search(const float* __restrict__ z,
                                                    const float* __restrict__ cbf,
                                                    float* __restrict__ outq,
                                                    float* __restrict__ loss) {
    __shared__ unsigned int cbL[KC * 16];   // 32 KB fp8 image (tile order)
    __shared__ unsigned int iniT[128];      // 512 ini bytes, [pl][t]
    __shared__ float redL[8];
    const int tid = threadIdx.x;
    const int lane = tid & 63, wid = tid >> 6;
    const int g = lane >> 4, pl = lane & 15;

    // ---- stage: fp32 codebook -> fp8 LDS in tile order + ini bytes --------
    for (int pass = 0; pass < 4; ++pass) {
        const int i = pass * 512 + tid;               // 0..2047 = t*64 + c*16 + pl
        const int r = ((i >> 6) << 4) | (i & 15);     // code row 16t+pl
        const int c = (i >> 4) & 3;                   // chunk
        const float* src = cbf + (size_t)r * DC + 8 * c;
        f32x4 a0 = *(const f32x4*)(src);
        f32x4 a1 = *(const f32x4*)(src + 4);
        f32x4 b0 = *(const f32x4*)(src + 32);
        f32x4 b1 = *(const f32x4*)(src + 36);
        a0 *= SE; a1 *= SE; b0 *= SE; b1 *= SE;
        i32x4 w = {pack4(a0[0], a0[1], a0[2], a0[3]),
                   pack4(a1[0], a1[1], a1[2], a1[3]),
                   pack4(b0[0], b0[1], b0[2], b0[3]),
                   pack4(b1[0], b1[1], b1[2], b1[3])};
        *(i32x4*)((char*)cbL + (size_t)i * 16) = w;   // linear: conflict-free
        float ss = 0.f;
#pragma unroll
        for (int k = 0; k < 4; ++k) {
            ss = fmaf(a0[k], a0[k], ss); ss = fmaf(a1[k], a1[k], ss);
            ss = fmaf(b0[k], b0[k], ss); ss = fmaf(b1[k], b1[k], ss);
        }
        ss += __shfl_xor(ss, 16, 64);                 // sum the 4 chunks
        ss += __shfl_xor(ss, 32, 64);                 // (lanes pl+16c share pl)
        if (c == 0) {
            int w8 = pk8<false>(-0.0625f * ss, 0.f, 0);
            ((unsigned char*)iniT)[(r & 15) * 32 + (r >> 4)] = (unsigned char)(w8 & 0xff);
        }
    }
    __syncthreads();

    const int wg = blockIdx.x * 8 + wid;         // 0..4095
    const int p0 = wg * 32;
    const int b  = p0 >> 12;                     // 32 | 4096 -> same b per wave
    const int s0 = (p0 & (HWs - 1)) + pl;
    const float* zbase = z + (size_t)b * (DC * HWs) + s0;

    // ---- z: 2 points (pl, pl+16) x 16 dims; fp32 kept + fp8 B-frags -------
    float zt[32];
#pragma unroll
    for (int j = 0; j < 8; ++j) {
        zt[j]      = zbase[(size_t)(8 * g + j) * HWs];
        zt[8 + j]  = zbase[(size_t)(32 + 8 * g + j) * HWs];
        zt[16 + j] = zbase[(size_t)(8 * g + j) * HWs + 16];
        zt[24 + j] = zbase[(size_t)(32 + 8 * g + j) * HWs + 16];
    }
    const long zA0 = mk64(pack4(SZ * zt[0],  SZ * zt[1],  SZ * zt[2],  SZ * zt[3]),
                          pack4(SZ * zt[4],  SZ * zt[5],  SZ * zt[6],  SZ * zt[7]));
    const long zA1 = mk64(pack4(SZ * zt[8],  SZ * zt[9],  SZ * zt[10], SZ * zt[11]),
                          pack4(SZ * zt[12], SZ * zt[13], SZ * zt[14], SZ * zt[15]));
    const long zB0 = mk64(pack4(SZ * zt[16], SZ * zt[17], SZ * zt[18], SZ * zt[19]),
                          pack4(SZ * zt[20], SZ * zt[21], SZ * zt[22], SZ * zt[23]));
    const long zB1 = mk64(pack4(SZ * zt[24], SZ * zt[25], SZ * zt[26], SZ * zt[27]),
                          pack4(SZ * zt[28], SZ * zt[29], SZ * zt[30], SZ * zt[31]));

    // per-lane ini bytes for codes 16t+pl, t=0..31
    const i32x4 iw0 = *(const i32x4*)((const char*)iniT + pl * 32);
    const i32x4 iw1 = *(const i32x4*)((const char*)iniT + pl * 32 + 16);
    const unsigned gmask = (g == 0) ? 0xffu : 0u;
    const long bunit = (g == 0) ? 0x38L : 0L;    // fp8 1.0 at k=0
    const f32x4 cb4 = {CBASE, CBASE, CBASE, CBASE};
    const char* cbbase = (const char*)cbL + lane * 16;

    unsigned best0 = 0u, best1 = 0u;
#pragma unroll
    for (int t = 0; t < 32; ++t) {
        const unsigned wrd = (t < 16) ? (unsigned)iw0[(t >> 2) & 3]
                                      : (unsigned)iw1[((t - 16) >> 2) & 3];
        const long a_ini = (long)((wrd >> ((t & 3) * 8)) & gmask);
        i32x4 aw = *(const i32x4*)(cbbase + (size_t)t * 1024);   // linear in lane
        long A0 = mk64(aw[0], aw[1]);            // dims 8g..8g+7
        long A1 = mk64(aw[2], aw[3]);            // dims 32+8g..32+8g+7
        f32x4 ia = __builtin_amdgcn_mfma_f32_16x16x32_fp8_fp8(a_ini, bunit, cb4, 0, 0, 0);
        f32x4 acc0 = __builtin_amdgcn_mfma_f32_16x16x32_fp8_fp8(A0, zA0, ia, 0, 0, 0);
        acc0 = __builtin_amdgcn_mfma_f32_16x16x32_fp8_fp8(A1, zA1, acc0, 0, 0, 0);
        f32x4 acc1 = __builtin_amdgcn_mfma_f32_16x16x32_fp8_fp8(A0, zB0, ia, 0, 0, 0);
        acc1 = __builtin_amdgcn_mfma_f32_16x16x32_fp8_fp8(A1, zB1, acc1, 0, 0, 0);
#pragma unroll
        for (int j = 0; j < 4; ++j) {
            const unsigned code = (unsigned)(16 * t + 4 * g + j);
            unsigned u0 = __builtin_bit_cast(unsigned, acc0[j]) | code;
            unsigned u1 = __builtin_bit_cast(unsigned, acc1[j]) | code;
            best0 = best0 > u0 ? best0 : u0;
            best1 = best1 > u1 ? best1 : u1;
        }
    }

    // argmax across the 4 g-groups holding the same point
#pragma unroll
    for (int m = 16; m <= 32; m <<= 1) {
        unsigned o0 = (unsigned)__shfl_xor((int)best0, m, 64);
        unsigned o1 = (unsigned)__shfl_xor((int)best1, m, 64);
        best0 = best0 > o0 ? best0 : o0;
        best1 = best1 > o1 ? best1 : o1;
    }
    const int bidx0 = best0 & 511, bidx1 = best1 & 511;

    // epilogue: gather exact fp32 code rows (L2-hot), write out, loss
    float err = 0.f;
    float* obase = outq + (size_t)b * (DC * HWs) + s0;
    {
        const float* qp = cbf + (size_t)bidx0 * DC + 8 * g;
        f32x4 q0 = *(const f32x4*)(qp);
        f32x4 q1 = *(const f32x4*)(qp + 4);
        f32x4 q2 = *(const f32x4*)(qp + 32);
        f32x4 q3 = *(const f32x4*)(qp + 36);
#pragma unroll
        for (int j = 0; j < 4; ++j) {
            size_t o0_ = (size_t)(8 * g + j) * HWs;
            size_t o1_ = (size_t)(8 * g + 4 + j) * HWs;
            size_t o2_ = (size_t)(32 + 8 * g + j) * HWs;
            size_t o3_ = (size_t)(32 + 8 * g + 4 + j) * HWs;
            obase[o0_] = q0[j]; float d0 = q0[j] - zt[j];      err = fmaf(d0, d0, err);
            obase[o1_] = q1[j]; float d1 = q1[j] - zt[4 + j];  err = fmaf(d1, d1, err);
            obase[o2_] = q2[j]; float d2 = q2[j] - zt[8 + j];  err = fmaf(d2, d2, err);
            obase[o3_] = q3[j]; float d3 = q3[j] - zt[12 + j]; err = fmaf(d3, d3, err);
        }
    }
    {
        const float* qp = cbf + (size_t)bidx1 * DC + 8 * g;
        f32x4 q0 = *(const f32x4*)(qp);
        f32x4 q1 = *(const f32x4*)(qp + 4);
        f32x4 q2 = *(const f32x4*)(qp + 32);
        f32x4 q3 = *(const f32x4*)(qp + 36);
#pragma unroll
        for (int j = 0; j < 4; ++j) {
            size_t o0_ = (size_t)(8 * g + j) * HWs + 16;
            size_t o1_ = (size_t)(8 * g + 4 + j) * HWs + 16;
            size_t o2_ = (size_t)(32 + 8 * g + j) * HWs + 16;
            size_t o3_ = (size_t)(32 + 8 * g + 4 + j) * HWs + 16;
            obase[o0_] = q0[j]; float d0 = q0[j] - zt[16 + j]; err = fmaf(d0, d0, err);
            obase[o1_] = q1[j]; float d1 = q1[j] - zt[20 + j]; err = fmaf(d1, d1, err);
            obase[o2_] = q2[j]; float d2 = q2[j] - zt[24 + j]; err = fmaf(d2, d2, err);
            obase[o3_] = q3[j]; float d3 = q3[j] - zt[28 + j]; err = fmaf(d3, d3, err);
        }
    }

    // wave reduce -> block reduce -> one device atomicAdd per block
#pragma unroll
    for (int off = 32; off; off >>= 1) err += __shfl_down(err, off, 64);
    if (lane == 0) redL[wid] = err;
    __syncthreads();
    if (tid == 0) {
        float s = 0.f;
#pragma unroll
        for (int k = 0; k < 8; ++k) s += redL[k];
        atomicAdd(loss, s * (1.25f / 8388608.0f));
    }
}

extern "C" void kernel_launch(void* const* d_in, const int* in_sizes, int n_in,
                              void* d_out, int out_size, void* d_ws, size_t ws_size,
                              hipStream_t stream) {
    const float* z   = (const float*)d_in[0];    // [32,64,64,64] f32
    const float* cbf = (const float*)d_in[1];    // [512,64] f32
    float* outq = (float*)d_out;                 // 8388608 + 1 (loss)
    float* loss = outq + 8388608;

    hipMemsetAsync(loss, 0, 4, stream);          // zero the atomic target
    vq_search<<<NBLK, 512, 0, stream>>>(z, cbf, outq, loss);
}

// Round 13
// 27.585 us; speedup vs baseline: 1.3438x; 1.2263x over previous
//
#include <hip/hip_runtime.h>

typedef float f32x4  __attribute__((ext_vector_type(4)));
typedef float f32x16 __attribute__((ext_vector_type(16)));
typedef int   i32x4  __attribute__((ext_vector_type(4)));

#define KC 512
#define DC 64
#define HWs 4096
#define NBLK 512               // 8 waves/block, 32 pts/wave = 256 pts/block
#define SE 512.0f              // codebook scale (e' = 512 e)
#define SZ 64.0f               // z scale (z' = 64 z)
#define INV_SE 0.001953125f
#define CBASE 4096.0f          // keeps packed scores positive

template <bool HI>
static __device__ inline int pk8(float a, float b, int old) {
    return __builtin_amdgcn_cvt_pk_fp8_f32(a, b, old, HI);
}
template <int S>
static __device__ inline float dec8(int w) {
    return __builtin_amdgcn_cvt_f32_fp8(w, S);
}
static __device__ inline long mk64(int lo, int hi) {
    return (long)(((unsigned long)(unsigned)hi << 32) | (unsigned)lo);
}
static __device__ inline int pack4(float a, float b, float c, float d) {
    int w = pk8<false>(a, b, 0);
    return pk8<true>(c, d, w);
}
static __device__ inline unsigned umax(unsigned a, unsigned b) { return a > b ? a : b; }

// --- fused staging + 32x32x16 MFMA search ----------------------------------
// score = CBASE - 0.5*SZ*SE*||e||^2 + z'.e'  (argmax == argmin distance)
// LDS image: [t:16][ks:4][l:64] 8B entries; entry (t,ks,l) = fp8 of dims
// (l>>5)*8 + 16ks .. +8 of code row 32t + (l&31).  Loop read: ds_read_b64 at
// lane*8 (stride 8B, 2-way = free).  A/B k-map: k = (lane>>5)*8 + j.
// C/D map [m74/m101]: col=lane&31, row=(reg&3)+8*(reg>>2)+4*(lane>>5).
__global__ __launch_bounds__(512, 4) void vq_search(const float* __restrict__ z,
                                                    const float* __restrict__ cbf,
                                                    float* __restrict__ outq,
                                                    float* __restrict__ partial) {
    __shared__ unsigned int cbL[KC * 16];   // 32 KB fp8 image
    __shared__ i32x4 iniB[32];              // 512 ini bytes: [col][t]
    __shared__ float redL[8];
    const int tid = threadIdx.x;
    const int lane = tid & 63, wid = tid >> 6;
    const int col = lane & 31, h = lane >> 5;

    // ---- stage: coalesced cbf reads (champion mapping), remapped LDS write -
    for (int pass = 0; pass < 4; ++pass) {
        const int i = pass * 512 + tid;          // thread -> (row r, chunk c)
        const int r = i >> 2, c = i & 3;         // 4 consecutive threads = 1 row
        const float* src = cbf + (size_t)r * DC + 8 * c;
        f32x4 a0 = *(const f32x4*)(src);
        f32x4 a1 = *(const f32x4*)(src + 4);
        f32x4 b0 = *(const f32x4*)(src + 32);
        f32x4 b1 = *(const f32x4*)(src + 36);
        a0 *= SE; a1 *= SE; b0 *= SE; b1 *= SE;
        int u0 = pack4(a0[0], a0[1], a0[2], a0[3]);   // dims 8c..8c+3
        int u1 = pack4(a1[0], a1[1], a1[2], a1[3]);   // dims 8c+4..8c+7
        int u2 = pack4(b0[0], b0[1], b0[2], b0[3]);   // dims 32+8c..+3
        int u3 = pack4(b1[0], b1[1], b1[2], b1[3]);   // dims 32+8c+4..+7
        // db=c -> (ks=c>>1, half=c&1); db=c+4 -> (ks=(c>>1)+2, same half)
        const int t = r >> 5;
        const int l1 = (r & 31) + 32 * (c & 1);
        char* base = (char*)cbL + t * 2048 + l1 * 8;
        *(long*)(base + (c >> 1) * 512)       = mk64(u0, u1);
        *(long*)(base + ((c >> 1) + 2) * 512) = mk64(u2, u3);
        float ss = 0.f;
#pragma unroll
        for (int k = 0; k < 4; ++k) {
            ss = fmaf(a0[k], a0[k], ss); ss = fmaf(a1[k], a1[k], ss);
            ss = fmaf(b0[k], b0[k], ss); ss = fmaf(b1[k], b1[k], ss);
        }
        ss += __shfl_xor(ss, 1, 64);             // 4 chunks of one row are in
        ss += __shfl_xor(ss, 2, 64);             // 4 consecutive lanes
        if (c == 0) {
            int w8 = pk8<false>(-0.0625f * ss, 0.f, 0);   // -0.5*SZ*SE*||e||^2
            ((unsigned char*)iniB)[(r & 31) * 16 + (r >> 5)] = (unsigned char)(w8 & 0xff);
        }
    }
    __syncthreads();

    const int wg = blockIdx.x * 8 + wid;         // 0..4095
    const int p0 = wg * 32;
    const int b  = p0 >> 12;                     // 32 | 4096 -> same b per wave
    const float* zcol = z + (size_t)b * (DC * HWs) + (p0 & (HWs - 1)) + col;

    // ---- z -> fp8 B-frags: lane (col,h) packs dims h*8+16ks..+8 (coalesced)
    long zfr[4];
#pragma unroll
    for (int ks = 0; ks < 4; ++ks) {
        float v[8];
#pragma unroll
        for (int j = 0; j < 8; ++j)
            v[j] = zcol[(size_t)(h * 8 + ks * 16 + j) * HWs];
        zfr[ks] = mk64(pack4(SZ * v[0], SZ * v[1], SZ * v[2], SZ * v[3]),
                       pack4(SZ * v[4], SZ * v[5], SZ * v[6], SZ * v[7]));
    }

    const i32x4 iw = iniB[col];                  // ini bytes for rows 32t+col
    const unsigned gm = (h == 0) ? 0xffu : 0u;
    const long bunit = (h == 0) ? 0x38L : 0L;    // fp8 1.0 at k=0
    f32x16 cbv;
#pragma unroll
    for (int j = 0; j < 16; ++j) cbv[j] = CBASE;
    const char* cbbase = (const char*)cbL + lane * 8;

    unsigned best = 0u;
#pragma unroll 4
    for (int t = 0; t < 16; ++t) {
        const unsigned wrd = (unsigned)iw[t >> 2];
        const long a_ini = (long)((wrd >> ((t & 3) * 8)) & gm);
        f32x16 acc = __builtin_amdgcn_mfma_f32_32x32x16_fp8_fp8(a_ini, bunit, cbv, 0, 0, 0);
#pragma unroll
        for (int ks = 0; ks < 4; ++ks) {
            long A = *(const long*)(cbbase + t * 2048 + ks * 512);
            acc = __builtin_amdgcn_mfma_f32_32x32x16_fp8_fp8(A, zfr[ks], acc, 0, 0, 0);
        }
        unsigned u[16];
#pragma unroll
        for (int j = 0; j < 16; ++j) {
            const unsigned code = (unsigned)(32 * t + (j & 3) + 8 * (j >> 2) + 4 * h);
            u[j] = __builtin_bit_cast(unsigned, acc[j]) | code;
        }
#pragma unroll
        for (int s = 8; s; s >>= 1)
#pragma unroll
            for (int j = 0; j < s; ++j) u[j] = umax(u[j], u[j + s]);
        best = umax(best, u[0]);
    }

    // halves hold disjoint row sets; one swap completes the per-point argmax
    best = umax(best, (unsigned)__shfl_xor((int)best, 32, 64));
    const int bidx = best & 511;

    // ---- epilogue: decode code from LDS image, write out, loss ------------
    const int t2 = bidx >> 5, b31 = bidx & 31;
    const char* qbase = (const char*)cbL + t2 * 2048 + b31 * 8 + 1024 * h; // ks=2h
    float* ocol = outq + (size_t)b * (DC * HWs) + (p0 & (HWs - 1)) + col;
    float err = 0.f;
#pragma unroll
    for (int qb = 0; qb < 4; ++qb) {
        // dims 32h + 8qb .. +7  live at (ks = 2h + (qb>>1), l' = b31 + 32*(qb&1))
        const long w8 = *(const long*)(qbase + (qb >> 1) * 512 + (qb & 1) * 256);
        const int lo = (int)w8, hi = (int)(w8 >> 32);
        float q[8];
        q[0] = dec8<0>(lo) * INV_SE; q[1] = dec8<1>(lo) * INV_SE;
        q[2] = dec8<2>(lo) * INV_SE; q[3] = dec8<3>(lo) * INV_SE;
        q[4] = dec8<0>(hi) * INV_SE; q[5] = dec8<1>(hi) * INV_SE;
        q[6] = dec8<2>(hi) * INV_SE; q[7] = dec8<3>(hi) * INV_SE;
#pragma unroll
        for (int j = 0; j < 8; ++j) {
            const size_t off = (size_t)(32 * h + 8 * qb + j) * HWs;
            float zv = zcol[off];                // L2/L3-hot reload, coalesced
            ocol[off] = q[j];                    // full-line store
            float d = q[j] - zv;
            err = fmaf(d, d, err);
        }
    }

    // wave -> block -> per-block partial
#pragma unroll
    for (int off = 32; off; off >>= 1) err += __shfl_down(err, off, 64);
    if (lane == 0) redL[wid] = err;
    __syncthreads();
    if (tid == 0) {
        float s = 0.f;
#pragma unroll
        for (int k = 0; k < 8; ++k) s += redL[k];
        partial[blockIdx.x] = s;
    }
}

// --- final loss reduction ----------------------------------------------------
__global__ __launch_bounds__(256) void vq_loss(const float* __restrict__ partial,
                                               float* __restrict__ loss_out) {
    float s = partial[threadIdx.x] + partial[threadIdx.x + 256];
#pragma unroll
    for (int off = 32; off; off >>= 1) s += __shfl_down(s, off, 64);
    __shared__ float red[4];
    if ((threadIdx.x & 63) == 0) red[threadIdx.x >> 6] = s;
    __syncthreads();
    if (threadIdx.x == 0)
        loss_out[0] = 1.25f * ((red[0] + red[1]) + (red[2] + red[3])) / 8388608.0f;
}

extern "C" void kernel_launch(void* const* d_in, const int* in_sizes, int n_in,
                              void* d_out, int out_size, void* d_ws, size_t ws_size,
                              hipStream_t stream) {
    const float* z   = (const float*)d_in[0];    // [32,64,64,64] f32
    const float* cbf = (const float*)d_in[1];    // [512,64] f32
    float* outq = (float*)d_out;                 // 8388608 + 1 (loss)
    float* loss = outq + 8388608;
    float* partial = (float*)d_ws;               // 512 f32

    vq_search<<<NBLK, 512, 0, stream>>>(z, cbf, outq, partial);
    vq_loss<<<1, 256, 0, stream>>>(partial, loss);
}

// Round 14
// 25.094 us; speedup vs baseline: 1.4772x; 1.0993x over previous
//
#include <hip/hip_runtime.h>

typedef float f32x4  __attribute__((ext_vector_type(4)));
typedef float f32x16 __attribute__((ext_vector_type(16)));
typedef int   i32x4  __attribute__((ext_vector_type(4)));

#define KC 512
#define DC 64
#define HWs 4096
#define NBLK 512               // 8 waves/block, 32 pts/wave = 256 pts/block
#define SE 512.0f              // codebook scale (e' = 512 e)
#define SZ 64.0f               // z scale (z' = 64 z)
#define INV_SE 0.001953125f
#define CBASE 4096.0f          // keeps packed scores positive

template <bool HI>
static __device__ inline int pk8(float a, float b, int old) {
    return __builtin_amdgcn_cvt_pk_fp8_f32(a, b, old, HI);
}
template <int S>
static __device__ inline float dec8(int w) {
    return __builtin_amdgcn_cvt_f32_fp8(w, S);
}
static __device__ inline long mk64(int lo, int hi) {
    return (long)(((unsigned long)(unsigned)hi << 32) | (unsigned)lo);
}
static __device__ inline int pack4(float a, float b, float c, float d) {
    int w = pk8<false>(a, b, 0);
    return pk8<true>(c, d, w);
}
static __device__ inline unsigned umax(unsigned a, unsigned b) { return a > b ? a : b; }

// --- fused staging + 32x32x16 MFMA search, wave-role skew -------------------
// Waves 0-3 stage the fp8 codebook image while waves 4-7 load z; after the
// barrier the roles swap (stagers fetch z under the loaders' compute).
// score = CBASE - 0.5*SZ*SE*||e||^2 + z'.e'  (argmax == argmin distance)
// LDS image: [t:16][ks:4][l:64] 8B entries; entry (t,ks,l) = fp8 of dims
// (l>>5)*8 + 16ks..+8 of code 32t+(l&31). Loop read ds_read_b64 at lane*8:
// stride 8B -> 2-way, free. C/D map: col=lane&31, row=(reg&3)+8*(reg>>2)+4h.
__global__ __launch_bounds__(512, 4) void vq_search(const float* __restrict__ z,
                                                    const float* __restrict__ cbf,
                                                    float* __restrict__ outq,
                                                    float* __restrict__ partial) {
    __shared__ unsigned int cbL[KC * 16];   // 32 KB fp8 image
    __shared__ i32x4 iniB[32];              // 512 ini bytes: [col][t]
    __shared__ float redL[8];
    const int tid = threadIdx.x;
    const int lane = tid & 63, wid = tid >> 6;
    const int col = lane & 31, h = lane >> 5;
    const int wg = blockIdx.x * 8 + wid;         // 0..4095
    const int p0 = wg * 32;
    const int b  = p0 >> 12;                     // 32 | 4096 -> same b per wave
    const float* zcol = z + (size_t)b * (DC * HWs) + (p0 & (HWs - 1)) + col;

    float zt[32];      // fp32 z, kept for loss (dims 16ks+8h+j)
    long  zfr[4];      // fp8 B-frags

    if (wid >= 4) {
        // ---- loader role: z burst #1 (overlaps the other waves' staging) --
#pragma unroll
        for (int ks = 0; ks < 4; ++ks)
#pragma unroll
            for (int j = 0; j < 8; ++j)
                zt[ks * 8 + j] = zcol[(size_t)(16 * ks + 8 * h + j) * HWs];
#pragma unroll
        for (int ks = 0; ks < 4; ++ks)
            zfr[ks] = mk64(
                pack4(SZ * zt[ks * 8 + 0], SZ * zt[ks * 8 + 1],
                      SZ * zt[ks * 8 + 2], SZ * zt[ks * 8 + 3]),
                pack4(SZ * zt[ks * 8 + 4], SZ * zt[ks * 8 + 5],
                      SZ * zt[ks * 8 + 6], SZ * zt[ks * 8 + 7]));
    } else {
        // ---- stager role: fp32 cbf (coalesced) -> fp8 LDS image + ini -----
        for (int pass = 0; pass < 8; ++pass) {
            const int i = pass * 256 + tid;           // tid < 256 here
            const int r = i >> 2, c = i & 3;          // 4 lanes = 1 row
            const float* src = cbf + (size_t)r * DC + 8 * c;
            f32x4 a0 = *(const f32x4*)(src);
            f32x4 a1 = *(const f32x4*)(src + 4);
            f32x4 b0 = *(const f32x4*)(src + 32);
            f32x4 b1 = *(const f32x4*)(src + 36);
            a0 *= SE; a1 *= SE; b0 *= SE; b1 *= SE;
            int u0 = pack4(a0[0], a0[1], a0[2], a0[3]);   // dims 8c..8c+3
            int u1 = pack4(a1[0], a1[1], a1[2], a1[3]);   // dims 8c+4..8c+7
            int u2 = pack4(b0[0], b0[1], b0[2], b0[3]);   // dims 32+8c..+3
            int u3 = pack4(b1[0], b1[1], b1[2], b1[3]);   // dims 32+8c+4..+7
            const int t = r >> 5;
            const int l1 = (r & 31) + 32 * (c & 1);
            char* base = (char*)cbL + t * 2048 + l1 * 8;
            *(long*)(base + (c >> 1) * 512)       = mk64(u0, u1);
            *(long*)(base + ((c >> 1) + 2) * 512) = mk64(u2, u3);
            float ss = 0.f;
#pragma unroll
            for (int k = 0; k < 4; ++k) {
                ss = fmaf(a0[k], a0[k], ss); ss = fmaf(a1[k], a1[k], ss);
                ss = fmaf(b0[k], b0[k], ss); ss = fmaf(b1[k], b1[k], ss);
            }
            ss += __shfl_xor(ss, 1, 64);              // 4 chunks sit in 4
            ss += __shfl_xor(ss, 2, 64);              // consecutive lanes
            if (c == 0) {
                int w8 = pk8<false>(-0.0625f * ss, 0.f, 0);
                ((unsigned char*)iniB)[(r & 31) * 16 + (r >> 5)] =
                    (unsigned char)(w8 & 0xff);
            }
        }
    }
    __syncthreads();

    if (wid < 4) {
        // ---- stager waves: z burst #2 (overlaps loader waves' tile loop) --
#pragma unroll
        for (int ks = 0; ks < 4; ++ks)
#pragma unroll
            for (int j = 0; j < 8; ++j)
                zt[ks * 8 + j] = zcol[(size_t)(16 * ks + 8 * h + j) * HWs];
#pragma unroll
        for (int ks = 0; ks < 4; ++ks)
            zfr[ks] = mk64(
                pack4(SZ * zt[ks * 8 + 0], SZ * zt[ks * 8 + 1],
                      SZ * zt[ks * 8 + 2], SZ * zt[ks * 8 + 3]),
                pack4(SZ * zt[ks * 8 + 4], SZ * zt[ks * 8 + 5],
                      SZ * zt[ks * 8 + 6], SZ * zt[ks * 8 + 7]));
    }

    // ---- tile loop: 16 x (ini-MFMA + 4 MFMA), conflict-free b64 reads -----
    const i32x4 iw = iniB[col];                  // ini bytes for rows 32t+col
    const unsigned gm = (h == 0) ? 0xffu : 0u;
    const long bunit = (h == 0) ? 0x38L : 0L;    // fp8 1.0 at k=0
    f32x16 cbv;
#pragma unroll
    for (int j = 0; j < 16; ++j) cbv[j] = CBASE;
    const char* cbbase = (const char*)cbL + lane * 8;

    unsigned best = 0u;
#pragma unroll 4
    for (int t = 0; t < 16; ++t) {
        const unsigned wrd = (unsigned)iw[t >> 2];
        const long a_ini = (long)((wrd >> ((t & 3) * 8)) & gm);
        f32x16 acc = __builtin_amdgcn_mfma_f32_32x32x16_fp8_fp8(a_ini, bunit, cbv, 0, 0, 0);
#pragma unroll
        for (int ks = 0; ks < 4; ++ks) {
            long A = *(const long*)(cbbase + t * 2048 + ks * 512);
            acc = __builtin_amdgcn_mfma_f32_32x32x16_fp8_fp8(A, zfr[ks], acc, 0, 0, 0);
        }
        unsigned u[16];
#pragma unroll
        for (int j = 0; j < 16; ++j) {
            const unsigned code = (unsigned)(32 * t + (j & 3) + 8 * (j >> 2) + 4 * h);
            u[j] = __builtin_bit_cast(unsigned, acc[j]) | code;
        }
#pragma unroll
        for (int s = 8; s; s >>= 1)
#pragma unroll
            for (int j = 0; j < s; ++j) u[j] = umax(u[j], u[j + s]);
        best = umax(best, u[0]);
    }
    best = umax(best, (unsigned)__shfl_xor((int)best, 32, 64));
    const int bidx = best & 511;

    // ---- epilogue: decode code from LDS, store, loss from zt regs ---------
    // dims 8h+16ks+j of code bidx live at entry (t2, ks, l'=b31+32h)
    const int t2 = bidx >> 5, b31 = bidx & 31;
    const char* qbase = (const char*)cbL + t2 * 2048 + (b31 + 32 * h) * 8;
    float* ocol = outq + (size_t)b * (DC * HWs) + (p0 & (HWs - 1)) + col;
    float err = 0.f;
#pragma unroll
    for (int ks = 0; ks < 4; ++ks) {
        const long w8 = *(const long*)(qbase + ks * 512);
        const int lo = (int)w8, hi = (int)(w8 >> 32);
        float q[8];
        q[0] = dec8<0>(lo) * INV_SE; q[1] = dec8<1>(lo) * INV_SE;
        q[2] = dec8<2>(lo) * INV_SE; q[3] = dec8<3>(lo) * INV_SE;
        q[4] = dec8<0>(hi) * INV_SE; q[5] = dec8<1>(hi) * INV_SE;
        q[6] = dec8<2>(hi) * INV_SE; q[7] = dec8<3>(hi) * INV_SE;
#pragma unroll
        for (int j = 0; j < 8; ++j) {
            const size_t off = (size_t)(16 * ks + 8 * h + j) * HWs;
            ocol[off] = q[j];                     // 128B-line coalesced store
            float d = q[j] - zt[ks * 8 + j];      // z from registers
            err = fmaf(d, d, err);
        }
    }

    // wave -> block -> per-block partial
#pragma unroll
    for (int off = 32; off; off >>= 1) err += __shfl_down(err, off, 64);
    if (lane == 0) redL[wid] = err;
    __syncthreads();
    if (tid == 0) {
        float s = 0.f;
#pragma unroll
        for (int k = 0; k < 8; ++k) s += redL[k];
        partial[blockIdx.x] = s;
    }
}

// --- final loss reduction ----------------------------------------------------
__global__ __launch_bounds__(256) void vq_loss(const float* __restrict__ partial,
                                               float* __restrict__ loss_out) {
    float s = partial[threadIdx.x] + partial[threadIdx.x + 256];
#pragma unroll
    for (int off = 32; off; off >>= 1) s += __shfl_down(s, off, 64);
    __shared__ float red[4];
    if ((threadIdx.x & 63) == 0) red[threadIdx.x >> 6] = s;
    __syncthreads();
    if (threadIdx.x == 0)
        loss_out[0] = 1.25f * ((red[0] + red[1]) + (red[2] + red[3])) / 8388608.0f;
}

extern "C" void kernel_launch(void* const* d_in, const int* in_sizes, int n_in,
                              void* d_out, int out_size, void* d_ws, size_t ws_size,
                              hipStream_t stream) {
    const float* z   = (const float*)d_in[0];    // [32,64,64,64] f32
    const float* cbf = (const float*)d_in[1];    // [512,64] f32
    float* outq = (float*)d_out;                 // 8388608 + 1 (loss)
    float* loss = outq + 8388608;
    float* partial = (float*)d_ws;               // 512 f32

    vq_search<<<NBLK, 512, 0, stream>>>(z, cbf, outq, partial);
    vq_loss<<<1, 256, 0, stream>>>(partial, loss);
}

// Round 15
// 23.934 us; speedup vs baseline: 1.5488x; 1.0485x over previous
//
#include <hip/hip_runtime.h>

typedef float f32x4 __attribute__((ext_vector_type(4)));
typedef int   i32x4 __attribute__((ext_vector_type(4)));

#define KC 512
#define DC 64
#define HWs 4096
#define NPTS 131072
#define NGRP 4096              // 32 points per wave
#define NBLK 512               // 8 waves/block, 256 pts/block
#define SE 512.0f              // codebook scale (e' = 512 e)
#define SZ 64.0f               // z scale (z' = 64 z)
#define CBASE 4096.0f          // keeps packed scores positive

template <bool HI>
static __device__ inline int pk8(float a, float b, int old) {
    return __builtin_amdgcn_cvt_pk_fp8_f32(a, b, old, HI);
}
static __device__ inline long mk64(int lo, int hi) {
    return (long)(((unsigned long)(unsigned)hi << 32) | (unsigned)lo);
}
static __device__ inline int pack4(float a, float b, float c, float d) {
    int w = pk8<false>(a, b, 0);
    return pk8<true>(c, d, w);
}

// --- fused: staging + MFMA search (R8 champion + conflict-free LDS image) ---
// score = CBASE - 0.5*SZ*SE*||e||^2 + z'.e'  (argmax == argmin distance)
// norm folded into ini-MFMA (A byte0 on g==0 = fp8(-||e'||^2/16), B byte0=1.0).
// LDS image entry j = t*64 + g*16 + pl at byte j*16 holds dims [8g..8g+7] and
// [32+8g..+7] of code row 16t+pl.  Staging: coalesced global reads (4 lanes/
// row), scattered ~4-way LDS writes (cheap).  Loop read: byte lane*16+t*1024
// -> linear in lane -> conflict-free (was 8-way in R8).
__global__ __launch_bounds__(512, 4) void vq_search(const float* __restrict__ z,
                                                    const float* __restrict__ cbf,
                                                    float* __restrict__ outq,
                                                    float* __restrict__ partial) {
    __shared__ unsigned int cbL[KC * 16];   // 32 KB fp8 image (tile order)
    __shared__ unsigned int iniT[128];      // 512 ini bytes, [pl][t]
    __shared__ float redL[8];
    const int tid = threadIdx.x;
    const int lane = tid & 63, wid = tid >> 6;
    const int g = lane >> 4, pl = lane & 15;

    // ---- stage: fp32 codebook (coalesced) -> fp8 LDS image + ini bytes ----
    for (int pass = 0; pass < 4; ++pass) {
        const int i = pass * 512 + tid;               // 4 consecutive thr = 1 row
        const int r = i >> 2, c = i & 3;
        const float* src = cbf + (size_t)r * DC + 8 * c;
        f32x4 a0 = *(const f32x4*)(src);
        f32x4 a1 = *(const f32x4*)(src + 4);
        f32x4 b0 = *(const f32x4*)(src + 32);
        f32x4 b1 = *(const f32x4*)(src + 36);
        a0 *= SE; a1 *= SE; b0 *= SE; b1 *= SE;
        i32x4 w = {pack4(a0[0], a0[1], a0[2], a0[3]),     // dims 8c..8c+3
                   pack4(a1[0], a1[1], a1[2], a1[3]),     // dims 8c+4..8c+7
                   pack4(b0[0], b0[1], b0[2], b0[3]),     // dims 32+8c..+3
                   pack4(b1[0], b1[1], b1[2], b1[3])};    // dims 32+8c+4..+7
        // entry j = (r>>4)*64 + c*16 + (r&15); byte j*16
        *(i32x4*)((char*)cbL + (size_t)(r >> 4) * 1024 + c * 256 + (r & 15) * 16) = w;
        float ss = 0.f;
#pragma unroll
        for (int k = 0; k < 4; ++k) {
            ss = fmaf(a0[k], a0[k], ss); ss = fmaf(a1[k], a1[k], ss);
            ss = fmaf(b0[k], b0[k], ss); ss = fmaf(b1[k], b1[k], ss);
        }
        ss += __shfl_xor(ss, 1, 64);                  // sum the 4 chunks
        ss += __shfl_xor(ss, 2, 64);                  // (4 lanes share a row)
        if (c == 0) {
            int w8 = pk8<false>(-0.0625f * ss, 0.f, 0);
            ((unsigned char*)iniT)[(r & 15) * 32 + (r >> 4)] = (unsigned char)(w8 & 0xff);
        }
    }
    __syncthreads();

    const int wg = blockIdx.x * 8 + wid;         // 0..4095
    const int p0 = wg * 32;
    const int b  = p0 >> 12;                     // 32 | 4096 -> same b per wave
    const int s0 = (p0 & (HWs - 1)) + pl;
    const float* zbase = z + (size_t)b * (DC * HWs) + s0;

    // ---- z: 2 points (pl, pl+16) x 16 dims; fp32 kept + fp8 B-frags -------
    float zt[32];
#pragma unroll
    for (int j = 0; j < 8; ++j) {
        zt[j]      = zbase[(size_t)(8 * g + j) * HWs];
        zt[8 + j]  = zbase[(size_t)(32 + 8 * g + j) * HWs];
        zt[16 + j] = zbase[(size_t)(8 * g + j) * HWs + 16];
        zt[24 + j] = zbase[(size_t)(32 + 8 * g + j) * HWs + 16];
    }
    const long zA0 = mk64(pack4(SZ * zt[0],  SZ * zt[1],  SZ * zt[2],  SZ * zt[3]),
                          pack4(SZ * zt[4],  SZ * zt[5],  SZ * zt[6],  SZ * zt[7]));
    const long zA1 = mk64(pack4(SZ * zt[8],  SZ * zt[9],  SZ * zt[10], SZ * zt[11]),
                          pack4(SZ * zt[12], SZ * zt[13], SZ * zt[14], SZ * zt[15]));
    const long zB0 = mk64(pack4(SZ * zt[16], SZ * zt[17], SZ * zt[18], SZ * zt[19]),
                          pack4(SZ * zt[20], SZ * zt[21], SZ * zt[22], SZ * zt[23]));
    const long zB1 = mk64(pack4(SZ * zt[24], SZ * zt[25], SZ * zt[26], SZ * zt[27]),
                          pack4(SZ * zt[28], SZ * zt[29], SZ * zt[30], SZ * zt[31]));

    // per-lane ini bytes for codes 16t+pl, t=0..31
    const i32x4 iw0 = *(const i32x4*)((const char*)iniT + pl * 32);
    const i32x4 iw1 = *(const i32x4*)((const char*)iniT + pl * 32 + 16);
    const unsigned gmask = (g == 0) ? 0xffu : 0u;
    const long bunit = (g == 0) ? 0x38L : 0L;    // fp8 1.0 at k=0
    const f32x4 cb4 = {CBASE, CBASE, CBASE, CBASE};
    const char* cbbase = (const char*)cbL + lane * 16;   // linear in lane

    unsigned best0 = 0u, best1 = 0u;
#pragma unroll
    for (int t = 0; t < 32; ++t) {
        const unsigned wrd = (t < 16) ? (unsigned)iw0[(t >> 2) & 3]
                                      : (unsigned)iw1[((t - 16) >> 2) & 3];
        const long a_ini = (long)((wrd >> ((t & 3) * 8)) & gmask);
        i32x4 aw = *(const i32x4*)(cbbase + (size_t)t * 1024);   // conflict-free
        long A0 = mk64(aw[0], aw[1]);            // dims 8g..8g+7
        long A1 = mk64(aw[2], aw[3]);            // dims 32+8g..32+8g+7
        f32x4 ia = __builtin_amdgcn_mfma_f32_16x16x32_fp8_fp8(a_ini, bunit, cb4, 0, 0, 0);
        f32x4 acc0 = __builtin_amdgcn_mfma_f32_16x16x32_fp8_fp8(A0, zA0, ia, 0, 0, 0);
        acc0 = __builtin_amdgcn_mfma_f32_16x16x32_fp8_fp8(A1, zA1, acc0, 0, 0, 0);
        f32x4 acc1 = __builtin_amdgcn_mfma_f32_16x16x32_fp8_fp8(A0, zB0, ia, 0, 0, 0);
        acc1 = __builtin_amdgcn_mfma_f32_16x16x32_fp8_fp8(A1, zB1, acc1, 0, 0, 0);
#pragma unroll
        for (int j = 0; j < 4; ++j) {
            const unsigned code = (unsigned)(16 * t + 4 * g + j);
            unsigned u0 = __builtin_bit_cast(unsigned, acc0[j]) | code;
            unsigned u1 = __builtin_bit_cast(unsigned, acc1[j]) | code;
            best0 = best0 > u0 ? best0 : u0;
            best1 = best1 > u1 ? best1 : u1;
        }
    }

    // argmax across the 4 g-groups holding the same point
#pragma unroll
    for (int m = 16; m <= 32; m <<= 1) {
        unsigned o0 = (unsigned)__shfl_xor((int)best0, m, 64);
        unsigned o1 = (unsigned)__shfl_xor((int)best1, m, 64);
        best0 = best0 > o0 ? best0 : o0;
        best1 = best1 > o1 ? best1 : o1;
    }
    const int bidx0 = best0 & 511, bidx1 = best1 & 511;

    // epilogue: gather exact fp32 code rows (L2-hot), write out, loss
    float err = 0.f;
    float* obase = outq + (size_t)b * (DC * HWs) + s0;
    {
        const float* qp = cbf + (size_t)bidx0 * DC + 8 * g;
        f32x4 q0 = *(const f32x4*)(qp);
        f32x4 q1 = *(const f32x4*)(qp + 4);
        f32x4 q2 = *(const f32x4*)(qp + 32);
        f32x4 q3 = *(const f32x4*)(qp + 36);
#pragma unroll
        for (int j = 0; j < 4; ++j) {
            size_t o0_ = (size_t)(8 * g + j) * HWs;
            size_t o1_ = (size_t)(8 * g + 4 + j) * HWs;
            size_t o2_ = (size_t)(32 + 8 * g + j) * HWs;
            size_t o3_ = (size_t)(32 + 8 * g + 4 + j) * HWs;
            obase[o0_] = q0[j]; float d0 = q0[j] - zt[j];      err = fmaf(d0, d0, err);
            obase[o1_] = q1[j]; float d1 = q1[j] - zt[4 + j];  err = fmaf(d1, d1, err);
            obase[o2_] = q2[j]; float d2 = q2[j] - zt[8 + j];  err = fmaf(d2, d2, err);
            obase[o3_] = q3[j]; float d3 = q3[j] - zt[12 + j]; err = fmaf(d3, d3, err);
        }
    }
    {
        const float* qp = cbf + (size_t)bidx1 * DC + 8 * g;
        f32x4 q0 = *(const f32x4*)(qp);
        f32x4 q1 = *(const f32x4*)(qp + 4);
        f32x4 q2 = *(const f32x4*)(qp + 32);
        f32x4 q3 = *(const f32x4*)(qp + 36);
#pragma unroll
        for (int j = 0; j < 4; ++j) {
            size_t o0_ = (size_t)(8 * g + j) * HWs + 16;
            size_t o1_ = (size_t)(8 * g + 4 + j) * HWs + 16;
            size_t o2_ = (size_t)(32 + 8 * g + j) * HWs + 16;
            size_t o3_ = (size_t)(32 + 8 * g + 4 + j) * HWs + 16;
            obase[o0_] = q0[j]; float d0 = q0[j] - zt[16 + j]; err = fmaf(d0, d0, err);
            obase[o1_] = q1[j]; float d1 = q1[j] - zt[20 + j]; err = fmaf(d1, d1, err);
            obase[o2_] = q2[j]; float d2 = q2[j] - zt[24 + j]; err = fmaf(d2, d2, err);
            obase[o3_] = q3[j]; float d3 = q3[j] - zt[28 + j]; err = fmaf(d3, d3, err);
        }
    }

    // wave reduce -> per-wave partial
#pragma unroll
    for (int off = 32; off; off >>= 1) err += __shfl_down(err, off, 64);
    if (lane == 0) partial[wg] = err;
    (void)redL;
}

// --- final loss reduction ---------------------------------------------------
__global__ __launch_bounds__(256) void vq_loss(const float* __restrict__ partial,
                                               float* __restrict__ loss_out) {
    float s = 0.f;
#pragma unroll
    for (int q = 0; q < NGRP / 256; ++q) s += partial[q * 256 + threadIdx.x];
#pragma unroll
    for (int off = 32; off; off >>= 1) s += __shfl_down(s, off, 64);
    __shared__ float red[4];
    if ((threadIdx.x & 63) == 0) red[threadIdx.x >> 6] = s;
    __syncthreads();
    if (threadIdx.x == 0)
        loss_out[0] = 1.25f * ((red[0] + red[1]) + (red[2] + red[3])) / 8388608.0f;
}

extern "C" void kernel_launch(void* const* d_in, const int* in_sizes, int n_in,
                              void* d_out, int out_size, void* d_ws, size_t ws_size,
                              hipStream_t stream) {
    const float* z   = (const float*)d_in[0];    // [32,64,64,64] f32
    const float* cbf = (const float*)d_in[1];    // [512,64] f32
    float* outq = (float*)d_out;                 // 8388608 + 1 (loss)
    float* loss = outq + 8388608;
    float* partial = (float*)d_ws;               // 4096 f32

    vq_search<<<NBLK, 512, 0, stream>>>(z, cbf, outq, partial);
    vq_loss<<<1, 256, 0, stream>>>(partial, loss);
}